// Round 8
// baseline (473.270 us; speedup 1.0000x reference)
//
#include <hip/hip_runtime.h>
#include <cstdint>
#include <cmath>

// B=8, x reshaped (8,15,512,512) fp32.
// gating: conv7x7 s2 p3 (15->64, 256x256) -> BN -> relu -> maxpool3x3 s2 p1 -> mean -> FC(64->3) -> top-1
// expert (selected, top-1 => gate weight 1.0): conv7x7 s2 p3 (15->64) relu -> conv3x3 s2 p1 (64->128) relu
//         -> conv3x3 s1 p1 (128->128)+b relu -> conv1x1 (128->5)+b
// out: hm | wh | reg | 0.01*aux = 655361 floats
//
// R7: 2-phase global_load_lds pipeline in all conv kernels (724 -> 574 us).
// R8: vectorized pool_k (574 -> 503 us). conv7m R8 structure = local optimum.
// R9 (REVERTED): 2-row/8-wave blocks regressed.
// R10: conv3m swizzle+depth2 good; conv7m bundle regressed.
// R11: super-chunk kept on conv3m; conv7m 66KB-LDS variant regressed.
// R12 A/B: conv7m<0,SWZ=0> = 89-90us (R8 repro); conv7m<1,SWZ=1> fell below the
//   top-5 cutoff (<88.8us) with FETCH halved -> XCD swizzle alone is the win;
//   R10's conv7m regression was the af-depth-2 component. (472us total)
// R13: apply SWZ=1 to the gating conv7m as well (mechanism proven same-kernel,
//   same-bench). No other changes.
// R14: resubmit of R13 — previous round failed on container infra, never ran.
// Fragment mappings (validated R3/R4): A[m=lane&15][k=quad*8+j],
// B[k=quad*8+j][n=lane&15], C[row=quad*4+r][col=lane&15].

typedef _Float16 f16x8 __attribute__((ext_vector_type(8)));
typedef _Float16 f16x4 __attribute__((ext_vector_type(4)));
typedef float f32x4 __attribute__((ext_vector_type(4)));

__device__ __forceinline__ void g2l16(const void* g, void* l) {
  __builtin_amdgcn_global_load_lds((__attribute__((address_space(1))) void*)g,
                                   (__attribute__((address_space(3))) void*)l,
                                   16, 0, 0);
}

// chunked XCD swizzle: nwg % 8 == 0; XCD (bid&7) owns a contiguous logical range
__device__ __forceinline__ int xcd_swz(int bid, int nwg) {
  return (bid & 7) * (nwg >> 3) + (bid >> 3);
}

// ---------------- prep: x fp32 [b][15][512][512] -> fp16 [b][512][512][16] ----------------
__global__ __launch_bounds__(256) void prep_x_k(
    const float* __restrict__ x, _Float16* __restrict__ xp)
{
  const int t = blockIdx.x * 256 + threadIdx.x;   // 0 .. 8*262144-1
  const int pix = t & 262143;
  const int b   = t >> 18;
  const float* src = x + (size_t)b * 15 * 262144 + pix;
  f16x8 lo, hi;
#pragma unroll
  for (int c = 0; c < 8; ++c)  lo[c] = (_Float16)src[(size_t)c * 262144];
#pragma unroll
  for (int c = 8; c < 15; ++c) hi[c - 8] = (_Float16)src[(size_t)c * 262144];
  hi[7] = (_Float16)0.f;
  *(f16x8*)&xp[(size_t)t * 16]     = lo;
  *(f16x8*)&xp[(size_t)t * 16 + 8] = hi;
}

// ---------------- prep: conv7 weights -> [set4][ky7][pair4][cout64][32] fp16 ----------------
__global__ __launch_bounds__(256) void prep_w7_k(
    const float* __restrict__ gw, const float* __restrict__ ew,
    _Float16* __restrict__ wp)
{
  const int i = blockIdx.x * 256 + threadIdx.x;   // 0 .. 229375
  const int kk   = i & 31;
  const int cout = (i >> 5) & 63;
  const int pair = (i >> 11) & 3;
  const int v    = i >> 13;
  const int ky = v % 7, set = v / 7;
  const int t = kk >> 4, cin = kk & 15;
  const int kx = 2 * pair + t;
  float val = 0.f;
  if (cin < 15 && kx < 7) {
    if (set == 0) val = gw[((cout * 15 + cin) * 7 + ky) * 7 + kx];
    else          val = ew[((((set - 1) * 64 + cout) * 15 + cin) * 7 + ky) * 7 + kx];
  }
  wp[i] = (_Float16)val;
}

// ---------------- prep: 3x3 weights [3][128][CINC][3][3] -> [e][tap9][ch][cout128][32] ----
template<int CINC>
__global__ __launch_bounds__(256) void prep_w3_k(
    const float* __restrict__ w, _Float16* __restrict__ wp)
{
  constexpr int CH = CINC / 32;
  const int i = blockIdx.x * 256 + threadIdx.x;   // 0 .. 3*9*CH*128*32-1
  const int kk   = i & 31;
  const int cout = (i >> 5) & 127;
  int rest = i >> 12;
  const int ch  = rest % CH;  rest /= CH;
  const int tap = rest % 9;
  const int e   = rest / 9;
  const int cin = ch * 32 + kk;
  wp[i] = (_Float16)w[((size_t)(e * 128 + cout) * CINC + cin) * 9 + tap];
}

// ---------------- conv7x7 s2 p3 (16ch-last in, 64ch-last fp16 out) ----------------
// EXACT R8 structure (best measured): 2 row buffers [518px][16ch], af depth-1,
// chunk barrier per ky. SWZ adds only the XCD block swizzle (R12: verified win).
template<int MODE, int SWZ>
__global__ __launch_bounds__(256, 3) void conv7m_k(
    const _Float16* __restrict__ xp, const _Float16* __restrict__ wp,
    const float* __restrict__ bn_g, const float* __restrict__ bn_b,
    const float* __restrict__ bn_m, const float* __restrict__ bn_v,
    const int* __restrict__ sel, _Float16* __restrict__ out)
{
  constexpr int ROWF = 518 * 16;                 // 8288 f16 per row buffer
  __shared__ __align__(16) _Float16 smem[18432]; // 36864 B (dbuf 33152 B | epi 36864 B)
  const int sb = SWZ ? xcd_swz(blockIdx.x, 2048) : (int)blockIdx.x;
  const int oy = sb & 255, b = sb >> 8;
  const int wv = threadIdx.x >> 6, lane = threadIdx.x & 63;
  const int ln15 = lane & 15, quad = lane >> 4;
  const int npx0 = wv * 64;

  int set = 0;
  if constexpr (MODE == 1) set = 1 + sel[b];
  const _Float16* wset = wp + (size_t)set * (7 * 4 * 64 * 32);
  const _Float16* xb   = xp + (size_t)b * (512 * 512 * 16);

  const _Float16* xrow[7];
  bool rowok[7];
#pragma unroll
  for (int ky = 0; ky < 7; ++ky) {
    const int iy = 2 * oy - 3 + ky;
    rowok[ky] = (unsigned)iy < 512u;
    const int iyc = iy < 0 ? 0 : (iy > 511 ? 511 : iy);
    xrow[ky] = xb + (size_t)iyc * (512 * 16);
  }

  // zero halo granules (p 0..2 -> g0..5, p 515..517 -> g1030..1035) of both buffers
  if (threadIdx.x < 32) {
    const int bi = threadIdx.x >> 4, k = threadIdx.x & 15;
    if (k < 12) {
      const int g = (k < 6) ? k : (1030 + k - 6);
      f16x8 z = {};
      *(f16x8*)&smem[bi * ROWF + g * 8] = z;
    }
  }

  f32x4 acc[4][4];
#pragma unroll
  for (int f = 0; f < 4; ++f)
#pragma unroll
    for (int g = 0; g < 4; ++g) acc[f][g] = (f32x4){0.f, 0.f, 0.f, 0.f};

  auto load_af = [&](int t, f16x8* af) {
    const int ky = t >> 2, pair = t & 3;
    const _Float16* wt = wset + (size_t)((ky * 4 + pair) * 64) * 32;
#pragma unroll
    for (int f = 0; f < 4; ++f)
      af[f] = *(const f16x8*)&wt[(f * 16 + ln15) * 32 + quad * 8];
  };
  // interior = px 3..514 -> granules 6..1029 (1024 granules = 16 segs of 1KB)
  auto stage = [&](int ky, int bi) {
    _Float16* bufb = &smem[bi * ROWF];
    const _Float16* xr = xrow[ky];
#pragma unroll
    for (int s = 0; s < 4; ++s) {
      const int seg = wv * 4 + s;
      const int gl = 6 + seg * 64 + lane;          // linear LDS granule
      const int gs = gl ^ ((gl >> 3) & 7);         // pre-swizzled source granule
      g2l16(xr + (size_t)((gs >> 1) - 3) * 16 + (gs & 1) * 8,
            bufb + (6 + seg * 64) * 8);
    }
  };

  int gb[4];
#pragma unroll
  for (int g = 0; g < 4; ++g)
    gb[g] = 4 * (npx0 + g * 16 + ln15) + quad;     // granule at pair 0

  f16x8 afA[4], afB[4];
  load_af(0, afA);
  stage(0, 0);
  __syncthreads();

#pragma unroll
  for (int t = 0; t < 28; ++t) {                   // minis = (ky 0..6) x (pair 0..3)
    const int ky = t >> 2, pair = t & 3;
    const int cur = ky & 1;
    f16x8* afc = (t & 1) ? afB : afA;
    f16x8* afn = (t & 1) ? afA : afB;
    if (t + 1 < 28) load_af(t + 1, afn);           // af prefetch BEFORE stage (vmcnt FIFO)
    if (pair == 0 && ky + 1 < 7) stage(ky + 1, cur ^ 1);
    if (rowok[ky]) {
      const _Float16* bufb = &smem[cur * ROWF];
#pragma unroll
      for (int g = 0; g < 4; ++g) {
        const int gq = gb[g] + 4 * pair;
        const int gs = gq ^ ((gq >> 3) & 7);
        const f16x8 bf = *(const f16x8*)&bufb[gs * 8];
#pragma unroll
        for (int f = 0; f < 4; ++f)
          acc[f][g] = __builtin_amdgcn_mfma_f32_16x16x32_f16(afc[f], bf, acc[f][g], 0, 0, 0);
      }
    }
    if (pair == 3) __syncthreads();                // drain stage(ky+1) + handoff buffers
  }

  // ---- epilogue: BN/relu -> LDS stage -> full-line stores ----
  _Float16* sw = &smem[wv * 4608];
#pragma unroll
  for (int f = 0; f < 4; ++f) {
    float scl[4], add[4];
#pragma unroll
    for (int r = 0; r < 4; ++r) {
      const int cout = f * 16 + quad * 4 + r;
      if constexpr (MODE == 0) {
        const float sc = bn_g[cout] * rsqrtf(bn_v[cout] + 1e-5f);
        scl[r] = sc; add[r] = bn_b[cout] - bn_m[cout] * sc;
      } else { scl[r] = 1.f; add[r] = 0.f; }
    }
#pragma unroll
    for (int g = 0; g < 4; ++g) {
      f16x4 h;
#pragma unroll
      for (int r = 0; r < 4; ++r)
        h[r] = (_Float16)fmaxf(acc[f][g][r] * scl[r] + add[r], 0.f);
      *(f16x4*)&sw[(g * 16 + ln15) * 72 + f * 16 + quad * 4] = h;
    }
  }
  __syncthreads();
  const size_t rowbase = ((size_t)(b * 256 + oy) * 256 + npx0) * 64;
#pragma unroll
  for (int i = 0; i < 8; ++i) {
    const int pxl = (lane >> 3) + i * 8;
    const int c8  = (lane & 7) * 8;
    const f16x8 v = *(const f16x8*)&sw[pxl * 72 + c8];
    *(f16x8*)&out[rowbase + (size_t)pxl * 64 + c8] = v;
  }
}

// ---------------- conv3x3 (CINC ch-last fp16 in, 128 ch-last fp16 out) ----------------
// R11 config (current best): 4 row-chunk buffers, super-chunk staging, XCD
// swizzle, af depth-2. LDS: 4 buffers (halo zeroed); epilogue reuses.
template<int CINC, int S, int INSZ, int OUTSZ, int MODE>
__global__ __launch_bounds__(256, 3) void conv3m_k(
    const _Float16* __restrict__ xp, const _Float16* __restrict__ wp,
    const float* __restrict__ p_bias, const int* __restrict__ sel,
    _Float16* __restrict__ out)
{
  constexpr int CH  = CINC / 32;
  constexpr int NCH = 3 * CH;                      // chunks = (ky, ch), ky-major; even
  constexpr int NT  = NCH * 3;                     // minis = (chunk, kx)
  constexpr int NPX = (S == 1) ? (OUTSZ + 2) : (2 * OUTSZ + 1);
  constexpr int ROWF = NPX * 32;                   // f16 per chunk buffer
  constexpr int NGR  = NPX * 4;                    // granules per chunk buffer
  constexpr int SPW  = INSZ / 64;                  // stage issues per wave per chunk
  constexpr int SMEMF = (4 * ROWF > 18432) ? 4 * ROWF : 18432;
  __shared__ __align__(16) _Float16 smem[SMEMF];
  const int sb = xcd_swz(blockIdx.x, OUTSZ * 8);   // XCD owns one image's oy range
  const int oy = sb % OUTSZ, b = sb / OUTSZ;
  const int wv = threadIdx.x >> 6, lane = threadIdx.x & 63;
  const int ln15 = lane & 15, quad = lane >> 4;
  const int mwb = (wv >> 1) * 64, nwb = (wv & 1) * 64;

  const int e = sel[b];
  const _Float16* we = wp + (size_t)e * (9 * CH * 128 * 32);
  const _Float16* xb = xp + (size_t)b * ((size_t)INSZ * INSZ * CINC);

  const _Float16* xrow[3];
  bool rowok[3];
#pragma unroll
  for (int ky = 0; ky < 3; ++ky) {
    const int iy = S * oy + ky - 1;
    rowok[ky] = (unsigned)iy < (unsigned)INSZ;
    const int iyc = iy < 0 ? 0 : (iy >= INSZ ? INSZ - 1 : iy);
    xrow[ky] = xb + (size_t)iyc * INSZ * CINC;
  }

  // zero halo granules of all 4 buffers (s1: p0 and p OUTSZ+1; s2: p0 only)
  {
    constexpr int HGPB = (S == 1) ? 8 : 4;
    if (threadIdx.x < 4 * HGPB) {
      const int bi = threadIdx.x / HGPB, k = threadIdx.x % HGPB;
      const int g = (k < 4) ? k : (NGR - 8 + k);
      f16x8 z = {};
      *(f16x8*)&smem[bi * ROWF + g * 8] = z;
    }
  }

  f32x4 acc[4][4];
#pragma unroll
  for (int f = 0; f < 4; ++f)
#pragma unroll
    for (int g = 0; g < 4; ++g) acc[f][g] = (f32x4){0.f, 0.f, 0.f, 0.f};

  auto load_af = [&](int t, f16x8* af) {
    const int c = t / 3, kx = t % 3;
    const int ky = c / CH, ch = c % CH;
    const _Float16* wt = we + (size_t)(((ky * 3 + kx) * CH + ch) * 128) * 32;
#pragma unroll
    for (int f = 0; f < 4; ++f)
      af[f] = *(const f16x8*)&wt[(mwb + f * 16 + ln15) * 32 + quad * 8];
  };
  // interior = px 1..INSZ -> granules 4..4+INSZ*4-1
  auto stage = [&](int c, int bi) {
    const int ky = c / CH, ch = c % CH;
    _Float16* bufb = &smem[bi * ROWF];
    const _Float16* xr = xrow[ky];
#pragma unroll
    for (int s = 0; s < SPW; ++s) {
      const int seg = wv * SPW + s;
      const int gl = 4 + seg * 64 + lane;          // linear LDS granule
      const int gs = gl ^ ((gl >> 3) & 7);         // pre-swizzled source granule
      g2l16(xr + (size_t)((gs >> 2) - 1) * CINC + ch * 32 + (gs & 3) * 8,
            bufb + (4 + seg * 64) * 8);
    }
  };

  int gb[4];
#pragma unroll
  for (int g = 0; g < 4; ++g) {
    const int ox = nwb + g * 16 + ln15;
    gb[g] = 4 * S * ox + quad;                     // granule at kx 0
  }

  // af prefetch depth 2 (kept from R10 — measured good on conv3m)
  f16x8 afb[3][4];
  load_af(0, afb[0]);
  load_af(1, afb[1]);
  stage(0, 0);
  stage(1, 1);
  __syncthreads();

#pragma unroll
  for (int t = 0; t < NT; ++t) {
    const int c = t / 3, kx = t % 3;
    const int ky = c / CH;
    const int cur = c & 3;                         // 4-buffer rotation
    if (t + 2 < NT) load_af(t + 2, afb[(t + 2) % 3]);  // issued BEFORE stage
    if (kx == 0 && (c & 1) == 0) {                 // super-chunk: stage 2 ahead
      if (c + 2 < NCH) stage(c + 2, (c + 2) & 3);
      if (c + 3 < NCH) stage(c + 3, (c + 3) & 3);
    }
    if (rowok[ky]) {
      const _Float16* bufb = &smem[cur * ROWF];
#pragma unroll
      for (int g = 0; g < 4; ++g) {
        const int gq = gb[g] + 4 * kx;
        const int gs = gq ^ ((gq >> 3) & 7);
        const f16x8 bf = *(const f16x8*)&bufb[gs * 8];
#pragma unroll
        for (int f = 0; f < 4; ++f)
          acc[f][g] = __builtin_amdgcn_mfma_f32_16x16x32_f16(afb[t % 3][f], bf, acc[f][g], 0, 0, 0);
      }
    }
    if (kx == 2 && (c & 1)) __syncthreads();       // drain once per super-chunk
  }

  // NCH is even -> last chunk is odd -> barrier already executed before here.
  // ---- epilogue: bias/relu -> LDS stage -> 128B half-line stores ----
  _Float16* sw = &smem[wv * 4608];
#pragma unroll
  for (int f = 0; f < 4; ++f) {
#pragma unroll
    for (int g = 0; g < 4; ++g) {
      f16x4 h;
#pragma unroll
      for (int r = 0; r < 4; ++r) {
        const int cout = mwb + f * 16 + quad * 4 + r;
        float v = acc[f][g][r];
        if constexpr (MODE == 2) v += p_bias[e * 128 + cout];
        h[r] = (_Float16)fmaxf(v, 0.f);
      }
      *(f16x4*)&sw[(g * 16 + ln15) * 72 + f * 16 + quad * 4] = h;
    }
  }
  __syncthreads();
  const size_t rowbase = ((size_t)(b * OUTSZ + oy) * OUTSZ + nwb) * 128 + mwb;
#pragma unroll
  for (int i = 0; i < 8; ++i) {
    const int pxl = (lane >> 3) + i * 8;
    const int c8  = (lane & 7) * 8;
    const f16x8 v = *(const f16x8*)&sw[pxl * 72 + c8];
    *(f16x8*)&out[rowbase + (size_t)pxl * 128 + c8] = v;
  }
}

// ---------------- zero pooled accumulator ----------------
__global__ void zero_k(float* __restrict__ pooled) {
  if (threadIdx.x < 512) pooled[threadIdx.x] = 0.f;
}

// ---------------- maxpool 3x3 s2 p1 (ch-last fp16) + partial mean ----------------
// R8: vectorized; R10: XCD swizzle. Packed f16 max is exact (inputs are f16).
__global__ __launch_bounds__(256) void pool_k(
    const _Float16* __restrict__ f, float* __restrict__ pooled)
{
  const int sb = xcd_swz(blockIdx.x, 1024);        // XCD owns one image's py range
  const int b  = sb >> 7;
  const int py = sb & 127;
  const int wv = threadIdx.x >> 6, lane = threadIdx.x & 63;
  const int c8  = (lane & 7) * 8;
  const int pxq = lane >> 3;
  const _Float16* fb = f + (size_t)b * 256 * 256 * 64;

  const int y0 = 2 * py - 1;
  float s[8];
#pragma unroll
  for (int j = 0; j < 8; ++j) s[j] = 0.f;

#pragma unroll
  for (int step = 0; step < 4; ++step) {
    const int px = wv * 32 + step * 8 + pxq;       // 0..127
    const int x0 = 2 * px - 1;
    f16x8 m;
#pragma unroll
    for (int j = 0; j < 8; ++j) m[j] = (_Float16)(-60000.f);
#pragma unroll
    for (int dy = 0; dy < 3; ++dy) {
      const int y = y0 + dy;
      if ((unsigned)y < 256u) {                    // wave-uniform (only py=0 clips)
        const _Float16* row = fb + (size_t)y * 256 * 64 + c8;
        if (x0 >= 0)                               // only px==0 lane clips
          m = __builtin_elementwise_max(m, *(const f16x8*)&row[(size_t)x0 * 64]);
        m = __builtin_elementwise_max(m, *(const f16x8*)&row[(size_t)(x0 + 1) * 64]);
        m = __builtin_elementwise_max(m, *(const f16x8*)&row[(size_t)(x0 + 2) * 64]);
      }
    }
#pragma unroll
    for (int j = 0; j < 8; ++j) s[j] += (float)m[j];
  }

  __shared__ float red[256][8];
#pragma unroll
  for (int j = 0; j < 8; ++j) red[threadIdx.x][j] = s[j];
  __syncthreads();
  if (threadIdx.x < 64) {
    const int c = threadIdx.x, cg = c >> 3, cj = c & 7;
    float t = 0.f;
#pragma unroll
    for (int k = 0; k < 32; ++k)                   // 4 waves x 8 px subgroups
      t += red[(k >> 3) * 64 + (k & 7) * 8 + cg][cj];
    atomicAdd(&pooled[b * 64 + c], t);
  }
}

// ---------------- FC + top-1 + aux loss (pooled holds SUMS; /16384) ----------------
__global__ __launch_bounds__(64) void gate_k(
    const float* __restrict__ pooled, const float* __restrict__ fcw,
    const float* __restrict__ fcb, int* __restrict__ sel, float* __restrict__ out_aux)
{
  __shared__ float probs[8][3];
  __shared__ int sidx[8];
  const int b = threadIdx.x;
  if (b < 8) {
    float l[3];
#pragma unroll
    for (int e = 0; e < 3; ++e) {
      float s = fcb[e];
      for (int c = 0; c < 64; ++c)
        s = fmaf(pooled[b * 64 + c] * (1.f / 16384.f), fcw[e * 64 + c], s);
      l[e] = s;
    }
    int best = 0;
    if (l[1] > l[best]) best = 1;
    if (l[2] > l[best]) best = 2;
    sel[b] = best;
    sidx[b] = best;
    const float m = fmaxf(l[0], fmaxf(l[1], l[2]));
    const float e0 = expf(l[0] - m), e1 = expf(l[1] - m), e2 = expf(l[2] - m);
    const float inv = 1.f / (e0 + e1 + e2);
    probs[b][0] = e0 * inv; probs[b][1] = e1 * inv; probs[b][2] = e2 * inv;
  }
  __syncthreads();
  if (threadIdx.x == 0) {
    float cnt[3] = {0.f, 0.f, 0.f}, pr[3] = {0.f, 0.f, 0.f};
    for (int bb = 0; bb < 8; ++bb) {
      cnt[sidx[bb]] += 1.f;
#pragma unroll
      for (int e = 0; e < 3; ++e) pr[e] += probs[bb][e];
    }
    float aux = 0.f;
#pragma unroll
    for (int e = 0; e < 3; ++e) aux += (cnt[e] * 0.125f) * (pr[e] * 0.125f);
    *out_aux = 0.01f * (3.f * aux);
  }
}

// ---------------- head 1x1 conv 128->5 + bias (ch-last fp16 in), scatter ----------------
__global__ __launch_bounds__(256) void head2m_k(
    const _Float16* __restrict__ in, const float* __restrict__ w,
    const float* __restrict__ b2, const int* __restrict__ sel,
    float* __restrict__ out)
{
  const int b = blockIdx.x >> 6;
  const int p = ((blockIdx.x & 63) << 8) + threadIdx.x;  // 0..16383
  const int e = sel[b];
  const float* wp = w + (size_t)e * 5 * 128;
  const _Float16* ip = in + ((size_t)(b << 14) + p) * 128;
  float a0 = 0.f, a1 = 0.f, a2 = 0.f, a3 = 0.f, a4 = 0.f;
#pragma unroll
  for (int cc = 0; cc < 16; ++cc) {
    const f16x8 v8 = *(const f16x8*)&ip[cc * 8];
#pragma unroll
    for (int j = 0; j < 8; ++j) {
      const float v = (float)v8[j];
      const int c = cc * 8 + j;
      a0 = fmaf(v, wp[c], a0);
      a1 = fmaf(v, wp[128 + c], a1);
      a2 = fmaf(v, wp[256 + c], a2);
      a3 = fmaf(v, wp[384 + c], a3);
      a4 = fmaf(v, wp[512 + c], a4);
    }
  }
  a0 += b2[e * 5 + 0]; a1 += b2[e * 5 + 1]; a2 += b2[e * 5 + 2];
  a3 += b2[e * 5 + 3]; a4 += b2[e * 5 + 4];
  out[(b << 14) + p] = a0;                         // hm
  out[131072 + ((b * 2 + 0) << 14) + p] = a1;      // wh c0
  out[131072 + ((b * 2 + 1) << 14) + p] = a2;      // wh c1
  out[393216 + ((b * 2 + 0) << 14) + p] = a3;      // reg c0
  out[393216 + ((b * 2 + 1) << 14) + p] = a4;      // reg c1
}

extern "C" void kernel_launch(void* const* d_in, const int* in_sizes, int n_in,
                              void* d_out, int out_size, void* d_ws, size_t ws_size,
                              hipStream_t stream) {
  const float* x          = (const float*)d_in[0];
  const float* g_conv_w   = (const float*)d_in[1];
  const float* g_bn_gamma = (const float*)d_in[2];
  const float* g_bn_beta  = (const float*)d_in[3];
  const float* g_bn_mean  = (const float*)d_in[4];
  const float* g_bn_var   = (const float*)d_in[5];
  const float* g_fc_w     = (const float*)d_in[6];
  const float* g_fc_b     = (const float*)d_in[7];
  const float* e_conv1_w  = (const float*)d_in[8];
  const float* e_conv2_w  = (const float*)d_in[9];
  const float* e_head_w1  = (const float*)d_in[10];
  const float* e_head_b1  = (const float*)d_in[11];
  const float* e_head_w2  = (const float*)d_in[12];
  const float* e_head_b2  = (const float*)d_in[13];
  float* out = (float*)d_out;

  // ---- workspace layout (f16 units), total ~170 MB ----
  _Float16* xp      = (_Float16*)d_ws;             // 8*512*512*16 = 33,554,432
  _Float16* featbuf = xp + 33554432;               // 8*256*256*64 = 33,554,432
  _Float16* y2      = featbuf + 33554432;          // 8*128*128*128 = 16,777,216
  _Float16* w7p     = y2 + 16777216;               // 229,376
  _Float16* w2p     = w7p + 229376;                // 221,184
  _Float16* w3p     = w2p + 221184;                // 442,368
  _Float16* y3      = xp;                          // head1 out aliases xp (dead by then)
  float*    pooled  = (float*)(w3p + 442368);      // 512 f32
  int*      sel     = (int*)(pooled + 512);        // 8 ints

  // ---- preps ----
  prep_x_k<<<8192, 256, 0, stream>>>(x, xp);
  prep_w7_k<<<896, 256, 0, stream>>>(g_conv_w, e_conv1_w, w7p);
  prep_w3_k<64><<<864, 256, 0, stream>>>(e_conv2_w, w2p);
  prep_w3_k<128><<<1728, 256, 0, stream>>>(e_head_w1, w3p);
  zero_k<<<1, 512, 0, stream>>>(pooled);

  // ---- gating path ----
  conv7m_k<0, 1><<<2048, 256, 0, stream>>>(xp, w7p, g_bn_gamma, g_bn_beta,
                                           g_bn_mean, g_bn_var, nullptr, featbuf);
  pool_k<<<1024, 256, 0, stream>>>(featbuf, pooled);
  gate_k<<<1, 64, 0, stream>>>(pooled, g_fc_w, g_fc_b, sel, out + 655360);

  // ---- selected-expert path ----
  conv7m_k<1, 1><<<2048, 256, 0, stream>>>(xp, w7p, nullptr, nullptr, nullptr, nullptr,
                                           sel, featbuf);
  conv3m_k<64, 2, 256, 128, 1><<<1024, 256, 0, stream>>>(featbuf, w2p, nullptr, sel, y2);
  conv3m_k<128, 1, 128, 128, 2><<<1024, 256, 0, stream>>>(y2, w3p, e_head_b1, sel, y3);
  head2m_k<<<512, 256, 0, stream>>>(y3, e_head_w2, e_head_b2, sel, out);
}

// Round 9
// 473.079 us; speedup vs baseline: 1.0004x; 1.0004x over previous
//
#include <hip/hip_runtime.h>
#include <cstdint>
#include <cmath>

// B=8, x reshaped (8,15,512,512) fp32.
// gating: conv7x7 s2 p3 (15->64, 256x256) -> BN -> relu -> maxpool3x3 s2 p1 -> mean -> FC(64->3) -> top-1
// expert (selected, top-1 => gate weight 1.0): conv7x7 s2 p3 (15->64) relu -> conv3x3 s2 p1 (64->128) relu
//         -> conv3x3 s1 p1 (128->128)+b relu -> conv1x1 (128->5)+b
// out: hm | wh | reg | 0.01*aux = 655361 floats
//
// R7: 2-phase global_load_lds pipeline in all conv kernels (724 -> 574 us).
// R8: vectorized pool_k (574 -> 503 us). conv7m R8 structure = local optimum.
// R9 (REVERTED), R10 (conv3m swz+depth2), R11 (conv3m super-chunk),
// R12 A/B (conv7m XCD swizzle attribution), R14 (both conv7m swizzled; FETCH
//   116->36MB but dur only 89->88: conv7m is NOT memory-bound — issue/latency
//   bound at 2-3 waves/SIMD with MfmaUtil 27%).
// R15: (a) T5 s_setprio(1) around MFMA clusters in conv7m/conv3m — waves
//   alternate stage/compute roles, the attn-like condition where setprio paid
//   (+4-7%), not the lockstep-GEMM null. (b) prep_x rewritten: float4 loads
//   (16B/lane, 4px/thread) + LDS transpose (granule-XOR swizzle) + coalesced
//   f16x8 stores (G13: scalar->vector loads ~2x on memory-bound kernels).
// Fragment mappings (validated R3/R4): A[m=lane&15][k=quad*8+j],
// B[k=quad*8+j][n=lane&15], C[row=quad*4+r][col=lane&15].

typedef _Float16 f16x8 __attribute__((ext_vector_type(8)));
typedef _Float16 f16x4 __attribute__((ext_vector_type(4)));
typedef float f32x4 __attribute__((ext_vector_type(4)));

__device__ __forceinline__ void g2l16(const void* g, void* l) {
  __builtin_amdgcn_global_load_lds((__attribute__((address_space(1))) void*)g,
                                   (__attribute__((address_space(3))) void*)l,
                                   16, 0, 0);
}

// chunked XCD swizzle: nwg % 8 == 0; XCD (bid&7) owns a contiguous logical range
__device__ __forceinline__ int xcd_swz(int bid, int nwg) {
  return (bid & 7) * (nwg >> 3) + (bid >> 3);
}

// ---------------- prep: x fp32 [b][15][512][512] -> fp16 [b][512][512][16] ----------------
// R15: float4 loads (4 px/thread), LDS transpose (XOR-swizzled 16B granules),
// coalesced stores. 2048 blocks x 256 threads; 1024 px per block.
__global__ __launch_bounds__(256) void prep_x_k(
    const float* __restrict__ x, _Float16* __restrict__ xp)
{
  __shared__ __align__(16) _Float16 st[16384];   // 2048 granules x 8 f16
  const int tid = threadIdx.x;
  const int b   = blockIdx.x >> 8;               // 8 images x 256 blocks
  const int blk = blockIdx.x & 255;
  const int px0 = blk * 1024;
  const float* src = x + (size_t)b * 15 * 262144 + px0 + tid * 4;

  f16x8 lo[4], hi[4];
#pragma unroll
  for (int j = 0; j < 4; ++j) hi[j][7] = (_Float16)0.f;
#pragma unroll
  for (int c = 0; c < 15; ++c) {
    const float4 v = *(const float4*)&src[(size_t)c * 262144];
    if (c < 8) {
      lo[0][c] = (_Float16)v.x; lo[1][c] = (_Float16)v.y;
      lo[2][c] = (_Float16)v.z; lo[3][c] = (_Float16)v.w;
    } else {
      hi[0][c - 8] = (_Float16)v.x; hi[1][c - 8] = (_Float16)v.y;
      hi[2][c - 8] = (_Float16)v.z; hi[3][c - 8] = (_Float16)v.w;
    }
  }
#pragma unroll
  for (int j = 0; j < 4; ++j) {
#pragma unroll
    for (int h = 0; h < 2; ++h) {
      const int g  = (tid * 4 + j) * 2 + h;      // px-major granule
      const int gs = g ^ ((g >> 3) & 7);         // bank-spread (same map on read)
      *(f16x8*)&st[gs * 8] = h ? hi[j] : lo[j];
    }
  }
  __syncthreads();
  _Float16* dst = xp + ((size_t)b * 262144 + px0) * 16;
#pragma unroll
  for (int m = 0; m < 4; ++m) {
    const int px = m * 256 + tid;
#pragma unroll
    for (int h = 0; h < 2; ++h) {
      const int g  = px * 2 + h;
      const int gs = g ^ ((g >> 3) & 7);
      *(f16x8*)&dst[(size_t)px * 16 + h * 8] = *(const f16x8*)&st[gs * 8];
    }
  }
}

// ---------------- prep: conv7 weights -> [set4][ky7][pair4][cout64][32] fp16 ----------------
__global__ __launch_bounds__(256) void prep_w7_k(
    const float* __restrict__ gw, const float* __restrict__ ew,
    _Float16* __restrict__ wp)
{
  const int i = blockIdx.x * 256 + threadIdx.x;   // 0 .. 229375
  const int kk   = i & 31;
  const int cout = (i >> 5) & 63;
  const int pair = (i >> 11) & 3;
  const int v    = i >> 13;
  const int ky = v % 7, set = v / 7;
  const int t = kk >> 4, cin = kk & 15;
  const int kx = 2 * pair + t;
  float val = 0.f;
  if (cin < 15 && kx < 7) {
    if (set == 0) val = gw[((cout * 15 + cin) * 7 + ky) * 7 + kx];
    else          val = ew[((((set - 1) * 64 + cout) * 15 + cin) * 7 + ky) * 7 + kx];
  }
  wp[i] = (_Float16)val;
}

// ---------------- prep: 3x3 weights [3][128][CINC][3][3] -> [e][tap9][ch][cout128][32] ----
template<int CINC>
__global__ __launch_bounds__(256) void prep_w3_k(
    const float* __restrict__ w, _Float16* __restrict__ wp)
{
  constexpr int CH = CINC / 32;
  const int i = blockIdx.x * 256 + threadIdx.x;   // 0 .. 3*9*CH*128*32-1
  const int kk   = i & 31;
  const int cout = (i >> 5) & 127;
  int rest = i >> 12;
  const int ch  = rest % CH;  rest /= CH;
  const int tap = rest % 9;
  const int e   = rest / 9;
  const int cin = ch * 32 + kk;
  wp[i] = (_Float16)w[((size_t)(e * 128 + cout) * CINC + cin) * 9 + tap];
}

// ---------------- conv7x7 s2 p3 (16ch-last in, 64ch-last fp16 out) ----------------
// EXACT R8 structure + XCD swizzle (R12) + R15 setprio around MFMA cluster.
template<int MODE, int SWZ>
__global__ __launch_bounds__(256, 3) void conv7m_k(
    const _Float16* __restrict__ xp, const _Float16* __restrict__ wp,
    const float* __restrict__ bn_g, const float* __restrict__ bn_b,
    const float* __restrict__ bn_m, const float* __restrict__ bn_v,
    const int* __restrict__ sel, _Float16* __restrict__ out)
{
  constexpr int ROWF = 518 * 16;                 // 8288 f16 per row buffer
  __shared__ __align__(16) _Float16 smem[18432]; // 36864 B (dbuf 33152 B | epi 36864 B)
  const int sb = SWZ ? xcd_swz(blockIdx.x, 2048) : (int)blockIdx.x;
  const int oy = sb & 255, b = sb >> 8;
  const int wv = threadIdx.x >> 6, lane = threadIdx.x & 63;
  const int ln15 = lane & 15, quad = lane >> 4;
  const int npx0 = wv * 64;

  int set = 0;
  if constexpr (MODE == 1) set = 1 + sel[b];
  const _Float16* wset = wp + (size_t)set * (7 * 4 * 64 * 32);
  const _Float16* xb   = xp + (size_t)b * (512 * 512 * 16);

  const _Float16* xrow[7];
  bool rowok[7];
#pragma unroll
  for (int ky = 0; ky < 7; ++ky) {
    const int iy = 2 * oy - 3 + ky;
    rowok[ky] = (unsigned)iy < 512u;
    const int iyc = iy < 0 ? 0 : (iy > 511 ? 511 : iy);
    xrow[ky] = xb + (size_t)iyc * (512 * 16);
  }

  // zero halo granules (p 0..2 -> g0..5, p 515..517 -> g1030..1035) of both buffers
  if (threadIdx.x < 32) {
    const int bi = threadIdx.x >> 4, k = threadIdx.x & 15;
    if (k < 12) {
      const int g = (k < 6) ? k : (1030 + k - 6);
      f16x8 z = {};
      *(f16x8*)&smem[bi * ROWF + g * 8] = z;
    }
  }

  f32x4 acc[4][4];
#pragma unroll
  for (int f = 0; f < 4; ++f)
#pragma unroll
    for (int g = 0; g < 4; ++g) acc[f][g] = (f32x4){0.f, 0.f, 0.f, 0.f};

  auto load_af = [&](int t, f16x8* af) {
    const int ky = t >> 2, pair = t & 3;
    const _Float16* wt = wset + (size_t)((ky * 4 + pair) * 64) * 32;
#pragma unroll
    for (int f = 0; f < 4; ++f)
      af[f] = *(const f16x8*)&wt[(f * 16 + ln15) * 32 + quad * 8];
  };
  // interior = px 3..514 -> granules 6..1029 (1024 granules = 16 segs of 1KB)
  auto stage = [&](int ky, int bi) {
    _Float16* bufb = &smem[bi * ROWF];
    const _Float16* xr = xrow[ky];
#pragma unroll
    for (int s = 0; s < 4; ++s) {
      const int seg = wv * 4 + s;
      const int gl = 6 + seg * 64 + lane;          // linear LDS granule
      const int gs = gl ^ ((gl >> 3) & 7);         // pre-swizzled source granule
      g2l16(xr + (size_t)((gs >> 1) - 3) * 16 + (gs & 1) * 8,
            bufb + (6 + seg * 64) * 8);
    }
  };

  int gb[4];
#pragma unroll
  for (int g = 0; g < 4; ++g)
    gb[g] = 4 * (npx0 + g * 16 + ln15) + quad;     // granule at pair 0

  f16x8 afA[4], afB[4];
  load_af(0, afA);
  stage(0, 0);
  __syncthreads();

#pragma unroll
  for (int t = 0; t < 28; ++t) {                   // minis = (ky 0..6) x (pair 0..3)
    const int ky = t >> 2, pair = t & 3;
    const int cur = ky & 1;
    f16x8* afc = (t & 1) ? afB : afA;
    f16x8* afn = (t & 1) ? afA : afB;
    if (t + 1 < 28) load_af(t + 1, afn);           // af prefetch BEFORE stage (vmcnt FIFO)
    if (pair == 0 && ky + 1 < 7) stage(ky + 1, cur ^ 1);
    if (rowok[ky]) {
      const _Float16* bufb = &smem[cur * ROWF];
      __builtin_amdgcn_s_setprio(1);               // T5: favor MFMA-issuing wave
#pragma unroll
      for (int g = 0; g < 4; ++g) {
        const int gq = gb[g] + 4 * pair;
        const int gs = gq ^ ((gq >> 3) & 7);
        const f16x8 bf = *(const f16x8*)&bufb[gs * 8];
#pragma unroll
        for (int f = 0; f < 4; ++f)
          acc[f][g] = __builtin_amdgcn_mfma_f32_16x16x32_f16(afc[f], bf, acc[f][g], 0, 0, 0);
      }
      __builtin_amdgcn_s_setprio(0);
    }
    if (pair == 3) __syncthreads();                // drain stage(ky+1) + handoff buffers
  }

  // ---- epilogue: BN/relu -> LDS stage -> full-line stores ----
  _Float16* sw = &smem[wv * 4608];
#pragma unroll
  for (int f = 0; f < 4; ++f) {
    float scl[4], add[4];
#pragma unroll
    for (int r = 0; r < 4; ++r) {
      const int cout = f * 16 + quad * 4 + r;
      if constexpr (MODE == 0) {
        const float sc = bn_g[cout] * rsqrtf(bn_v[cout] + 1e-5f);
        scl[r] = sc; add[r] = bn_b[cout] - bn_m[cout] * sc;
      } else { scl[r] = 1.f; add[r] = 0.f; }
    }
#pragma unroll
    for (int g = 0; g < 4; ++g) {
      f16x4 h;
#pragma unroll
      for (int r = 0; r < 4; ++r)
        h[r] = (_Float16)fmaxf(acc[f][g][r] * scl[r] + add[r], 0.f);
      *(f16x4*)&sw[(g * 16 + ln15) * 72 + f * 16 + quad * 4] = h;
    }
  }
  __syncthreads();
  const size_t rowbase = ((size_t)(b * 256 + oy) * 256 + npx0) * 64;
#pragma unroll
  for (int i = 0; i < 8; ++i) {
    const int pxl = (lane >> 3) + i * 8;
    const int c8  = (lane & 7) * 8;
    const f16x8 v = *(const f16x8*)&sw[pxl * 72 + c8];
    *(f16x8*)&out[rowbase + (size_t)pxl * 64 + c8] = v;
  }
}

// ---------------- conv3x3 (CINC ch-last fp16 in, 128 ch-last fp16 out) ----------------
// R11 config (current best): 4 row-chunk buffers, super-chunk staging, XCD
// swizzle, af depth-2. R15: setprio around MFMA cluster.
template<int CINC, int S, int INSZ, int OUTSZ, int MODE>
__global__ __launch_bounds__(256, 3) void conv3m_k(
    const _Float16* __restrict__ xp, const _Float16* __restrict__ wp,
    const float* __restrict__ p_bias, const int* __restrict__ sel,
    _Float16* __restrict__ out)
{
  constexpr int CH  = CINC / 32;
  constexpr int NCH = 3 * CH;                      // chunks = (ky, ch), ky-major; even
  constexpr int NT  = NCH * 3;                     // minis = (chunk, kx)
  constexpr int NPX = (S == 1) ? (OUTSZ + 2) : (2 * OUTSZ + 1);
  constexpr int ROWF = NPX * 32;                   // f16 per chunk buffer
  constexpr int NGR  = NPX * 4;                    // granules per chunk buffer
  constexpr int SPW  = INSZ / 64;                  // stage issues per wave per chunk
  constexpr int SMEMF = (4 * ROWF > 18432) ? 4 * ROWF : 18432;
  __shared__ __align__(16) _Float16 smem[SMEMF];
  const int sb = xcd_swz(blockIdx.x, OUTSZ * 8);   // XCD owns one image's oy range
  const int oy = sb % OUTSZ, b = sb / OUTSZ;
  const int wv = threadIdx.x >> 6, lane = threadIdx.x & 63;
  const int ln15 = lane & 15, quad = lane >> 4;
  const int mwb = (wv >> 1) * 64, nwb = (wv & 1) * 64;

  const int e = sel[b];
  const _Float16* we = wp + (size_t)e * (9 * CH * 128 * 32);
  const _Float16* xb = xp + (size_t)b * ((size_t)INSZ * INSZ * CINC);

  const _Float16* xrow[3];
  bool rowok[3];
#pragma unroll
  for (int ky = 0; ky < 3; ++ky) {
    const int iy = S * oy + ky - 1;
    rowok[ky] = (unsigned)iy < (unsigned)INSZ;
    const int iyc = iy < 0 ? 0 : (iy >= INSZ ? INSZ - 1 : iy);
    xrow[ky] = xb + (size_t)iyc * INSZ * CINC;
  }

  // zero halo granules of all 4 buffers (s1: p0 and p OUTSZ+1; s2: p0 only)
  {
    constexpr int HGPB = (S == 1) ? 8 : 4;
    if (threadIdx.x < 4 * HGPB) {
      const int bi = threadIdx.x / HGPB, k = threadIdx.x % HGPB;
      const int g = (k < 4) ? k : (NGR - 8 + k);
      f16x8 z = {};
      *(f16x8*)&smem[bi * ROWF + g * 8] = z;
    }
  }

  f32x4 acc[4][4];
#pragma unroll
  for (int f = 0; f < 4; ++f)
#pragma unroll
    for (int g = 0; g < 4; ++g) acc[f][g] = (f32x4){0.f, 0.f, 0.f, 0.f};

  auto load_af = [&](int t, f16x8* af) {
    const int c = t / 3, kx = t % 3;
    const int ky = c / CH, ch = c % CH;
    const _Float16* wt = we + (size_t)(((ky * 3 + kx) * CH + ch) * 128) * 32;
#pragma unroll
    for (int f = 0; f < 4; ++f)
      af[f] = *(const f16x8*)&wt[(mwb + f * 16 + ln15) * 32 + quad * 8];
  };
  // interior = px 1..INSZ -> granules 4..4+INSZ*4-1
  auto stage = [&](int c, int bi) {
    const int ky = c / CH, ch = c % CH;
    _Float16* bufb = &smem[bi * ROWF];
    const _Float16* xr = xrow[ky];
#pragma unroll
    for (int s = 0; s < SPW; ++s) {
      const int seg = wv * SPW + s;
      const int gl = 4 + seg * 64 + lane;          // linear LDS granule
      const int gs = gl ^ ((gl >> 3) & 7);         // pre-swizzled source granule
      g2l16(xr + (size_t)((gs >> 2) - 1) * CINC + ch * 32 + (gs & 3) * 8,
            bufb + (4 + seg * 64) * 8);
    }
  };

  int gb[4];
#pragma unroll
  for (int g = 0; g < 4; ++g) {
    const int ox = nwb + g * 16 + ln15;
    gb[g] = 4 * S * ox + quad;                     // granule at kx 0
  }

  // af prefetch depth 2 (kept from R10 — measured good on conv3m)
  f16x8 afb[3][4];
  load_af(0, afb[0]);
  load_af(1, afb[1]);
  stage(0, 0);
  stage(1, 1);
  __syncthreads();

#pragma unroll
  for (int t = 0; t < NT; ++t) {
    const int c = t / 3, kx = t % 3;
    const int ky = c / CH;
    const int cur = c & 3;                         // 4-buffer rotation
    if (t + 2 < NT) load_af(t + 2, afb[(t + 2) % 3]);  // issued BEFORE stage
    if (kx == 0 && (c & 1) == 0) {                 // super-chunk: stage 2 ahead
      if (c + 2 < NCH) stage(c + 2, (c + 2) & 3);
      if (c + 3 < NCH) stage(c + 3, (c + 3) & 3);
    }
    if (rowok[ky]) {
      const _Float16* bufb = &smem[cur * ROWF];
      __builtin_amdgcn_s_setprio(1);               // T5: favor MFMA-issuing wave
#pragma unroll
      for (int g = 0; g < 4; ++g) {
        const int gq = gb[g] + 4 * kx;
        const int gs = gq ^ ((gq >> 3) & 7);
        const f16x8 bf = *(const f16x8*)&bufb[gs * 8];
#pragma unroll
        for (int f = 0; f < 4; ++f)
          acc[f][g] = __builtin_amdgcn_mfma_f32_16x16x32_f16(afb[t % 3][f], bf, acc[f][g], 0, 0, 0);
      }
      __builtin_amdgcn_s_setprio(0);
    }
    if (kx == 2 && (c & 1)) __syncthreads();       // drain once per super-chunk
  }

  // NCH is even -> last chunk is odd -> barrier already executed before here.
  // ---- epilogue: bias/relu -> LDS stage -> 128B half-line stores ----
  _Float16* sw = &smem[wv * 4608];
#pragma unroll
  for (int f = 0; f < 4; ++f) {
#pragma unroll
    for (int g = 0; g < 4; ++g) {
      f16x4 h;
#pragma unroll
      for (int r = 0; r < 4; ++r) {
        const int cout = mwb + f * 16 + quad * 4 + r;
        float v = acc[f][g][r];
        if constexpr (MODE == 2) v += p_bias[e * 128 + cout];
        h[r] = (_Float16)fmaxf(v, 0.f);
      }
      *(f16x4*)&sw[(g * 16 + ln15) * 72 + f * 16 + quad * 4] = h;
    }
  }
  __syncthreads();
  const size_t rowbase = ((size_t)(b * OUTSZ + oy) * OUTSZ + nwb) * 128 + mwb;
#pragma unroll
  for (int i = 0; i < 8; ++i) {
    const int pxl = (lane >> 3) + i * 8;
    const int c8  = (lane & 7) * 8;
    const f16x8 v = *(const f16x8*)&sw[pxl * 72 + c8];
    *(f16x8*)&out[rowbase + (size_t)pxl * 128 + c8] = v;
  }
}

// ---------------- zero pooled accumulator ----------------
__global__ void zero_k(float* __restrict__ pooled) {
  if (threadIdx.x < 512) pooled[threadIdx.x] = 0.f;
}

// ---------------- maxpool 3x3 s2 p1 (ch-last fp16) + partial mean ----------------
// R8: vectorized; R10: XCD swizzle. Packed f16 max is exact (inputs are f16).
__global__ __launch_bounds__(256) void pool_k(
    const _Float16* __restrict__ f, float* __restrict__ pooled)
{
  const int sb = xcd_swz(blockIdx.x, 1024);        // XCD owns one image's py range
  const int b  = sb >> 7;
  const int py = sb & 127;
  const int wv = threadIdx.x >> 6, lane = threadIdx.x & 63;
  const int c8  = (lane & 7) * 8;
  const int pxq = lane >> 3;
  const _Float16* fb = f + (size_t)b * 256 * 256 * 64;

  const int y0 = 2 * py - 1;
  float s[8];
#pragma unroll
  for (int j = 0; j < 8; ++j) s[j] = 0.f;

#pragma unroll
  for (int step = 0; step < 4; ++step) {
    const int px = wv * 32 + step * 8 + pxq;       // 0..127
    const int x0 = 2 * px - 1;
    f16x8 m;
#pragma unroll
    for (int j = 0; j < 8; ++j) m[j] = (_Float16)(-60000.f);
#pragma unroll
    for (int dy = 0; dy < 3; ++dy) {
      const int y = y0 + dy;
      if ((unsigned)y < 256u) {                    // wave-uniform (only py=0 clips)
        const _Float16* row = fb + (size_t)y * 256 * 64 + c8;
        if (x0 >= 0)                               // only px==0 lane clips
          m = __builtin_elementwise_max(m, *(const f16x8*)&row[(size_t)x0 * 64]);
        m = __builtin_elementwise_max(m, *(const f16x8*)&row[(size_t)(x0 + 1) * 64]);
        m = __builtin_elementwise_max(m, *(const f16x8*)&row[(size_t)(x0 + 2) * 64]);
      }
    }
#pragma unroll
    for (int j = 0; j < 8; ++j) s[j] += (float)m[j];
  }

  __shared__ float red[256][8];
#pragma unroll
  for (int j = 0; j < 8; ++j) red[threadIdx.x][j] = s[j];
  __syncthreads();
  if (threadIdx.x < 64) {
    const int c = threadIdx.x, cg = c >> 3, cj = c & 7;
    float t = 0.f;
#pragma unroll
    for (int k = 0; k < 32; ++k)                   // 4 waves x 8 px subgroups
      t += red[(k >> 3) * 64 + (k & 7) * 8 + cg][cj];
    atomicAdd(&pooled[b * 64 + c], t);
  }
}

// ---------------- FC + top-1 + aux loss (pooled holds SUMS; /16384) ----------------
__global__ __launch_bounds__(64) void gate_k(
    const float* __restrict__ pooled, const float* __restrict__ fcw,
    const float* __restrict__ fcb, int* __restrict__ sel, float* __restrict__ out_aux)
{
  __shared__ float probs[8][3];
  __shared__ int sidx[8];
  const int b = threadIdx.x;
  if (b < 8) {
    float l[3];
#pragma unroll
    for (int e = 0; e < 3; ++e) {
      float s = fcb[e];
      for (int c = 0; c < 64; ++c)
        s = fmaf(pooled[b * 64 + c] * (1.f / 16384.f), fcw[e * 64 + c], s);
      l[e] = s;
    }
    int best = 0;
    if (l[1] > l[best]) best = 1;
    if (l[2] > l[best]) best = 2;
    sel[b] = best;
    sidx[b] = best;
    const float m = fmaxf(l[0], fmaxf(l[1], l[2]));
    const float e0 = expf(l[0] - m), e1 = expf(l[1] - m), e2 = expf(l[2] - m);
    const float inv = 1.f / (e0 + e1 + e2);
    probs[b][0] = e0 * inv; probs[b][1] = e1 * inv; probs[b][2] = e2 * inv;
  }
  __syncthreads();
  if (threadIdx.x == 0) {
    float cnt[3] = {0.f, 0.f, 0.f}, pr[3] = {0.f, 0.f, 0.f};
    for (int bb = 0; bb < 8; ++bb) {
      cnt[sidx[bb]] += 1.f;
#pragma unroll
      for (int e = 0; e < 3; ++e) pr[e] += probs[bb][e];
    }
    float aux = 0.f;
#pragma unroll
    for (int e = 0; e < 3; ++e) aux += (cnt[e] * 0.125f) * (pr[e] * 0.125f);
    *out_aux = 0.01f * (3.f * aux);
  }
}

// ---------------- head 1x1 conv 128->5 + bias (ch-last fp16 in), scatter ----------------
__global__ __launch_bounds__(256) void head2m_k(
    const _Float16* __restrict__ in, const float* __restrict__ w,
    const float* __restrict__ b2, const int* __restrict__ sel,
    float* __restrict__ out)
{
  const int b = blockIdx.x >> 6;
  const int p = ((blockIdx.x & 63) << 8) + threadIdx.x;  // 0..16383
  const int e = sel[b];
  const float* wp = w + (size_t)e * 5 * 128;
  const _Float16* ip = in + ((size_t)(b << 14) + p) * 128;
  float a0 = 0.f, a1 = 0.f, a2 = 0.f, a3 = 0.f, a4 = 0.f;
#pragma unroll
  for (int cc = 0; cc < 16; ++cc) {
    const f16x8 v8 = *(const f16x8*)&ip[cc * 8];
#pragma unroll
    for (int j = 0; j < 8; ++j) {
      const float v = (float)v8[j];
      const int c = cc * 8 + j;
      a0 = fmaf(v, wp[c], a0);
      a1 = fmaf(v, wp[128 + c], a1);
      a2 = fmaf(v, wp[256 + c], a2);
      a3 = fmaf(v, wp[384 + c], a3);
      a4 = fmaf(v, wp[512 + c], a4);
    }
  }
  a0 += b2[e * 5 + 0]; a1 += b2[e * 5 + 1]; a2 += b2[e * 5 + 2];
  a3 += b2[e * 5 + 3]; a4 += b2[e * 5 + 4];
  out[(b << 14) + p] = a0;                         // hm
  out[131072 + ((b * 2 + 0) << 14) + p] = a1;      // wh c0
  out[131072 + ((b * 2 + 1) << 14) + p] = a2;      // wh c1
  out[393216 + ((b * 2 + 0) << 14) + p] = a3;      // reg c0
  out[393216 + ((b * 2 + 1) << 14) + p] = a4;      // reg c1
}

extern "C" void kernel_launch(void* const* d_in, const int* in_sizes, int n_in,
                              void* d_out, int out_size, void* d_ws, size_t ws_size,
                              hipStream_t stream) {
  const float* x          = (const float*)d_in[0];
  const float* g_conv_w   = (const float*)d_in[1];
  const float* g_bn_gamma = (const float*)d_in[2];
  const float* g_bn_beta  = (const float*)d_in[3];
  const float* g_bn_mean  = (const float*)d_in[4];
  const float* g_bn_var   = (const float*)d_in[5];
  const float* g_fc_w     = (const float*)d_in[6];
  const float* g_fc_b     = (const float*)d_in[7];
  const float* e_conv1_w  = (const float*)d_in[8];
  const float* e_conv2_w  = (const float*)d_in[9];
  const float* e_head_w1  = (const float*)d_in[10];
  const float* e_head_b1  = (const float*)d_in[11];
  const float* e_head_w2  = (const float*)d_in[12];
  const float* e_head_b2  = (const float*)d_in[13];
  float* out = (float*)d_out;

  // ---- workspace layout (f16 units), total ~170 MB ----
  _Float16* xp      = (_Float16*)d_ws;             // 8*512*512*16 = 33,554,432
  _Float16* featbuf = xp + 33554432;               // 8*256*256*64 = 33,554,432
  _Float16* y2      = featbuf + 33554432;          // 8*128*128*128 = 16,777,216
  _Float16* w7p     = y2 + 16777216;               // 229,376
  _Float16* w2p     = w7p + 229376;                // 221,184
  _Float16* w3p     = w2p + 221184;                // 442,368
  _Float16* y3      = xp;                          // head1 out aliases xp (dead by then)
  float*    pooled  = (float*)(w3p + 442368);      // 512 f32
  int*      sel     = (int*)(pooled + 512);        // 8 ints

  // ---- preps ----
  prep_x_k<<<2048, 256, 0, stream>>>(x, xp);
  prep_w7_k<<<896, 256, 0, stream>>>(g_conv_w, e_conv1_w, w7p);
  prep_w3_k<64><<<864, 256, 0, stream>>>(e_conv2_w, w2p);
  prep_w3_k<128><<<1728, 256, 0, stream>>>(e_head_w1, w3p);
  zero_k<<<1, 512, 0, stream>>>(pooled);

  // ---- gating path ----
  conv7m_k<0, 1><<<2048, 256, 0, stream>>>(xp, w7p, g_bn_gamma, g_bn_beta,
                                           g_bn_mean, g_bn_var, nullptr, featbuf);
  pool_k<<<1024, 256, 0, stream>>>(featbuf, pooled);
  gate_k<<<1, 64, 0, stream>>>(pooled, g_fc_w, g_fc_b, sel, out + 655360);

  // ---- selected-expert path ----
  conv7m_k<1, 1><<<2048, 256, 0, stream>>>(xp, w7p, nullptr, nullptr, nullptr, nullptr,
                                           sel, featbuf);
  conv3m_k<64, 2, 256, 128, 1><<<1024, 256, 0, stream>>>(featbuf, w2p, nullptr, sel, y2);
  conv3m_k<128, 1, 128, 128, 2><<<1024, 256, 0, stream>>>(y2, w3p, e_head_b1, sel, y3);
  head2m_k<<<512, 256, 0, stream>>>(y3, e_head_w2, e_head_b2, sel, out);
}

// Round 10
// 457.748 us; speedup vs baseline: 1.0339x; 1.0335x over previous
//
#include <hip/hip_runtime.h>
#include <cstdint>
#include <cmath>

// B=8, x reshaped (8,15,512,512) fp32.
// gating: conv7x7 s2 p3 (15->64, 256x256) -> BN -> relu -> maxpool3x3 s2 p1 -> mean -> FC(64->3) -> top-1
// expert (selected, top-1 => gate weight 1.0): conv7x7 s2 p3 (15->64) relu -> conv3x3 s2 p1 (64->128) relu
//         -> conv3x3 s1 p1 (128->128)+b relu -> conv1x1 (128->5)+b
// out: hm | wh | reg | 0.01*aux = 655361 floats
//
// R7: 2-phase global_load_lds pipeline in all conv kernels (724 -> 574 us).
// R8: vectorized pool_k (574 -> 503 us). conv7m R8 structure = local optimum.
// R9 (REVERTED), R10 (conv3m swz+depth2), R11 (conv3m super-chunk),
// R12 A/B (conv7m XCD swizzle attribution, 472us), R14 (both conv7m swizzled;
//   FETCH 116->36MB but dur flat: conv7m is issue/latency-bound, not mem-bound).
// R15: setprio = NULL (barrier-locked waves, m190 regime); prep_x vectorized.
//   conv7m declared a structural plateau at ~87us / MfmaUtil 28%.
// R16: harvest the sub-cutoff time instead:
//  (a) head2m FUSED into conv3m<128> epilogue — block already holds all
//      128ch x 128px of a row; 1x1 conv = 320 fmaf/thread + quad shuffle
//      reduce + small LDS cross-wave reduce. Deletes y3 write (33.5MB),
//      head2m read (33.5MB), head2m dispatch, and the old staged-store
//      epilogue. v no longer rounds through fp16 (absmax can only improve).
//  (b) prep_w7 + prep_w3<64> + prep_w3<128> + zero_k merged into one
//      dispatch (branch on block range). 13 -> 8 dispatches in the graph.
// Fragment mappings (validated R3/R4): A[m=lane&15][k=quad*8+j],
// B[k=quad*8+j][n=lane&15], C[row=quad*4+r][col=lane&15].

typedef _Float16 f16x8 __attribute__((ext_vector_type(8)));
typedef _Float16 f16x4 __attribute__((ext_vector_type(4)));
typedef float f32x4 __attribute__((ext_vector_type(4)));

__device__ __forceinline__ void g2l16(const void* g, void* l) {
  __builtin_amdgcn_global_load_lds((__attribute__((address_space(1))) void*)g,
                                   (__attribute__((address_space(3))) void*)l,
                                   16, 0, 0);
}

// chunked XCD swizzle: nwg % 8 == 0; XCD (bid&7) owns a contiguous logical range
__device__ __forceinline__ int xcd_swz(int bid, int nwg) {
  return (bid & 7) * (nwg >> 3) + (bid >> 3);
}

// ---------------- prep: x fp32 [b][15][512][512] -> fp16 [b][512][512][16] ----------------
// R15: float4 loads (4 px/thread), LDS transpose (XOR-swizzled 16B granules),
// coalesced stores. 2048 blocks x 256 threads; 1024 px per block.
__global__ __launch_bounds__(256) void prep_x_k(
    const float* __restrict__ x, _Float16* __restrict__ xp)
{
  __shared__ __align__(16) _Float16 st[16384];   // 2048 granules x 8 f16
  const int tid = threadIdx.x;
  const int b   = blockIdx.x >> 8;               // 8 images x 256 blocks
  const int blk = blockIdx.x & 255;
  const int px0 = blk * 1024;
  const float* src = x + (size_t)b * 15 * 262144 + px0 + tid * 4;

  f16x8 lo[4], hi[4];
#pragma unroll
  for (int j = 0; j < 4; ++j) hi[j][7] = (_Float16)0.f;
#pragma unroll
  for (int c = 0; c < 15; ++c) {
    const float4 v = *(const float4*)&src[(size_t)c * 262144];
    if (c < 8) {
      lo[0][c] = (_Float16)v.x; lo[1][c] = (_Float16)v.y;
      lo[2][c] = (_Float16)v.z; lo[3][c] = (_Float16)v.w;
    } else {
      hi[0][c - 8] = (_Float16)v.x; hi[1][c - 8] = (_Float16)v.y;
      hi[2][c - 8] = (_Float16)v.z; hi[3][c - 8] = (_Float16)v.w;
    }
  }
#pragma unroll
  for (int j = 0; j < 4; ++j) {
#pragma unroll
    for (int h = 0; h < 2; ++h) {
      const int g  = (tid * 4 + j) * 2 + h;      // px-major granule
      const int gs = g ^ ((g >> 3) & 7);         // bank-spread (same map on read)
      *(f16x8*)&st[gs * 8] = h ? hi[j] : lo[j];
    }
  }
  __syncthreads();
  _Float16* dst = xp + ((size_t)b * 262144 + px0) * 16;
#pragma unroll
  for (int m = 0; m < 4; ++m) {
    const int px = m * 256 + tid;
#pragma unroll
    for (int h = 0; h < 2; ++h) {
      const int g  = px * 2 + h;
      const int gs = g ^ ((g >> 3) & 7);
      *(f16x8*)&dst[(size_t)px * 16 + h * 8] = *(const f16x8*)&st[gs * 8];
    }
  }
}

// ---------------- merged weight prep + pooled zero (R16) ----------------
// blocks [0,896): conv7 weights -> [set4][ky7][pair4][cout64][32]
// blocks [896,1760): conv2 weights (CINC=64) -> [e][tap9][ch2][cout128][32]
// blocks [1760,3488): head1 weights (CINC=128) -> [e][tap9][ch4][cout128][32]
// block 3488: zero pooled[512]
__global__ __launch_bounds__(256) void prep_w_k(
    const float* __restrict__ gw, const float* __restrict__ ew,
    const float* __restrict__ w2in, const float* __restrict__ w3in,
    _Float16* __restrict__ w7p, _Float16* __restrict__ w2p,
    _Float16* __restrict__ w3p, float* __restrict__ pooled)
{
  const int bid = blockIdx.x;
  if (bid < 896) {
    const int i = bid * 256 + threadIdx.x;        // 0 .. 229375
    const int kk   = i & 31;
    const int cout = (i >> 5) & 63;
    const int pair = (i >> 11) & 3;
    const int v    = i >> 13;
    const int ky = v % 7, set = v / 7;
    const int t = kk >> 4, cin = kk & 15;
    const int kx = 2 * pair + t;
    float val = 0.f;
    if (cin < 15 && kx < 7) {
      if (set == 0) val = gw[((cout * 15 + cin) * 7 + ky) * 7 + kx];
      else          val = ew[((((set - 1) * 64 + cout) * 15 + cin) * 7 + ky) * 7 + kx];
    }
    w7p[i] = (_Float16)val;
  } else if (bid < 1760) {
    const int i = (bid - 896) * 256 + threadIdx.x; // 0 .. 221183 (CH=2)
    const int kk   = i & 31;
    const int cout = (i >> 5) & 127;
    int rest = i >> 12;
    const int ch  = rest % 2;  rest /= 2;
    const int tap = rest % 9;
    const int e   = rest / 9;
    const int cin = ch * 32 + kk;
    w2p[i] = (_Float16)w2in[((size_t)(e * 128 + cout) * 64 + cin) * 9 + tap];
  } else if (bid < 3488) {
    const int i = (bid - 1760) * 256 + threadIdx.x; // 0 .. 442367 (CH=4)
    const int kk   = i & 31;
    const int cout = (i >> 5) & 127;
    int rest = i >> 12;
    const int ch  = rest % 4;  rest /= 4;
    const int tap = rest % 9;
    const int e   = rest / 9;
    const int cin = ch * 32 + kk;
    w3p[i] = (_Float16)w3in[((size_t)(e * 128 + cout) * 128 + cin) * 9 + tap];
  } else {
    pooled[threadIdx.x]       = 0.f;
    pooled[256 + threadIdx.x] = 0.f;
  }
}

// ---------------- conv7x7 s2 p3 (16ch-last in, 64ch-last fp16 out) ----------------
// EXACT R8 structure + XCD swizzle (R12). Plateau config (R15: setprio null).
template<int MODE, int SWZ>
__global__ __launch_bounds__(256, 3) void conv7m_k(
    const _Float16* __restrict__ xp, const _Float16* __restrict__ wp,
    const float* __restrict__ bn_g, const float* __restrict__ bn_b,
    const float* __restrict__ bn_m, const float* __restrict__ bn_v,
    const int* __restrict__ sel, _Float16* __restrict__ out)
{
  constexpr int ROWF = 518 * 16;                 // 8288 f16 per row buffer
  __shared__ __align__(16) _Float16 smem[18432]; // 36864 B (dbuf 33152 B | epi 36864 B)
  const int sb = SWZ ? xcd_swz(blockIdx.x, 2048) : (int)blockIdx.x;
  const int oy = sb & 255, b = sb >> 8;
  const int wv = threadIdx.x >> 6, lane = threadIdx.x & 63;
  const int ln15 = lane & 15, quad = lane >> 4;
  const int npx0 = wv * 64;

  int set = 0;
  if constexpr (MODE == 1) set = 1 + sel[b];
  const _Float16* wset = wp + (size_t)set * (7 * 4 * 64 * 32);
  const _Float16* xb   = xp + (size_t)b * (512 * 512 * 16);

  const _Float16* xrow[7];
  bool rowok[7];
#pragma unroll
  for (int ky = 0; ky < 7; ++ky) {
    const int iy = 2 * oy - 3 + ky;
    rowok[ky] = (unsigned)iy < 512u;
    const int iyc = iy < 0 ? 0 : (iy > 511 ? 511 : iy);
    xrow[ky] = xb + (size_t)iyc * (512 * 16);
  }

  // zero halo granules (p 0..2 -> g0..5, p 515..517 -> g1030..1035) of both buffers
  if (threadIdx.x < 32) {
    const int bi = threadIdx.x >> 4, k = threadIdx.x & 15;
    if (k < 12) {
      const int g = (k < 6) ? k : (1030 + k - 6);
      f16x8 z = {};
      *(f16x8*)&smem[bi * ROWF + g * 8] = z;
    }
  }

  f32x4 acc[4][4];
#pragma unroll
  for (int f = 0; f < 4; ++f)
#pragma unroll
    for (int g = 0; g < 4; ++g) acc[f][g] = (f32x4){0.f, 0.f, 0.f, 0.f};

  auto load_af = [&](int t, f16x8* af) {
    const int ky = t >> 2, pair = t & 3;
    const _Float16* wt = wset + (size_t)((ky * 4 + pair) * 64) * 32;
#pragma unroll
    for (int f = 0; f < 4; ++f)
      af[f] = *(const f16x8*)&wt[(f * 16 + ln15) * 32 + quad * 8];
  };
  // interior = px 3..514 -> granules 6..1029 (1024 granules = 16 segs of 1KB)
  auto stage = [&](int ky, int bi) {
    _Float16* bufb = &smem[bi * ROWF];
    const _Float16* xr = xrow[ky];
#pragma unroll
    for (int s = 0; s < 4; ++s) {
      const int seg = wv * 4 + s;
      const int gl = 6 + seg * 64 + lane;          // linear LDS granule
      const int gs = gl ^ ((gl >> 3) & 7);         // pre-swizzled source granule
      g2l16(xr + (size_t)((gs >> 1) - 3) * 16 + (gs & 1) * 8,
            bufb + (6 + seg * 64) * 8);
    }
  };

  int gb[4];
#pragma unroll
  for (int g = 0; g < 4; ++g)
    gb[g] = 4 * (npx0 + g * 16 + ln15) + quad;     // granule at pair 0

  f16x8 afA[4], afB[4];
  load_af(0, afA);
  stage(0, 0);
  __syncthreads();

#pragma unroll
  for (int t = 0; t < 28; ++t) {                   // minis = (ky 0..6) x (pair 0..3)
    const int ky = t >> 2, pair = t & 3;
    const int cur = ky & 1;
    f16x8* afc = (t & 1) ? afB : afA;
    f16x8* afn = (t & 1) ? afA : afB;
    if (t + 1 < 28) load_af(t + 1, afn);           // af prefetch BEFORE stage (vmcnt FIFO)
    if (pair == 0 && ky + 1 < 7) stage(ky + 1, cur ^ 1);
    if (rowok[ky]) {
      const _Float16* bufb = &smem[cur * ROWF];
#pragma unroll
      for (int g = 0; g < 4; ++g) {
        const int gq = gb[g] + 4 * pair;
        const int gs = gq ^ ((gq >> 3) & 7);
        const f16x8 bf = *(const f16x8*)&bufb[gs * 8];
#pragma unroll
        for (int f = 0; f < 4; ++f)
          acc[f][g] = __builtin_amdgcn_mfma_f32_16x16x32_f16(afc[f], bf, acc[f][g], 0, 0, 0);
      }
    }
    if (pair == 3) __syncthreads();                // drain stage(ky+1) + handoff buffers
  }

  // ---- epilogue: BN/relu -> LDS stage -> full-line stores ----
  _Float16* sw = &smem[wv * 4608];
#pragma unroll
  for (int f = 0; f < 4; ++f) {
    float scl[4], add[4];
#pragma unroll
    for (int r = 0; r < 4; ++r) {
      const int cout = f * 16 + quad * 4 + r;
      if constexpr (MODE == 0) {
        const float sc = bn_g[cout] * rsqrtf(bn_v[cout] + 1e-5f);
        scl[r] = sc; add[r] = bn_b[cout] - bn_m[cout] * sc;
      } else { scl[r] = 1.f; add[r] = 0.f; }
    }
#pragma unroll
    for (int g = 0; g < 4; ++g) {
      f16x4 h;
#pragma unroll
      for (int r = 0; r < 4; ++r)
        h[r] = (_Float16)fmaxf(acc[f][g][r] * scl[r] + add[r], 0.f);
      *(f16x4*)&sw[(g * 16 + ln15) * 72 + f * 16 + quad * 4] = h;
    }
  }
  __syncthreads();
  const size_t rowbase = ((size_t)(b * 256 + oy) * 256 + npx0) * 64;
#pragma unroll
  for (int i = 0; i < 8; ++i) {
    const int pxl = (lane >> 3) + i * 8;
    const int c8  = (lane & 7) * 8;
    const f16x8 v = *(const f16x8*)&sw[pxl * 72 + c8];
    *(f16x8*)&out[rowbase + (size_t)pxl * 64 + c8] = v;
  }
}

// ---------------- conv3x3 (CINC ch-last fp16 in, 128 ch-last fp16 out) ----------------
// R11 config: 4 row-chunk buffers, super-chunk staging, XCD swizzle, af depth-2.
// R16: MODE==2 fuses the 1x1 head (128->5 + bias) into the epilogue and writes
// the final float outputs directly (no y3 round-trip, no head2m kernel).
template<int CINC, int S, int INSZ, int OUTSZ, int MODE>
__global__ __launch_bounds__(256, 3) void conv3m_k(
    const _Float16* __restrict__ xp, const _Float16* __restrict__ wp,
    const float* __restrict__ p_bias, const int* __restrict__ sel,
    _Float16* __restrict__ out,
    const float* __restrict__ hw2, const float* __restrict__ hb2,
    float* __restrict__ hout)
{
  constexpr int CH  = CINC / 32;
  constexpr int NCH = 3 * CH;                      // chunks = (ky, ch), ky-major; even
  constexpr int NT  = NCH * 3;                     // minis = (chunk, kx)
  constexpr int NPX = (S == 1) ? (OUTSZ + 2) : (2 * OUTSZ + 1);
  constexpr int ROWF = NPX * 32;                   // f16 per chunk buffer
  constexpr int NGR  = NPX * 4;                    // granules per chunk buffer
  constexpr int SPW  = INSZ / 64;                  // stage issues per wave per chunk
  constexpr int SMEMF = (4 * ROWF > 18432) ? 4 * ROWF : 18432;
  __shared__ __align__(16) _Float16 smem[SMEMF];
  const int sb = xcd_swz(blockIdx.x, OUTSZ * 8);   // XCD owns one image's oy range
  const int oy = sb % OUTSZ, b = sb / OUTSZ;
  const int wv = threadIdx.x >> 6, lane = threadIdx.x & 63;
  const int ln15 = lane & 15, quad = lane >> 4;
  const int mwb = (wv >> 1) * 64, nwb = (wv & 1) * 64;

  const int e = sel[b];
  const _Float16* we = wp + (size_t)e * (9 * CH * 128 * 32);
  const _Float16* xb = xp + (size_t)b * ((size_t)INSZ * INSZ * CINC);

  const _Float16* xrow[3];
  bool rowok[3];
#pragma unroll
  for (int ky = 0; ky < 3; ++ky) {
    const int iy = S * oy + ky - 1;
    rowok[ky] = (unsigned)iy < (unsigned)INSZ;
    const int iyc = iy < 0 ? 0 : (iy >= INSZ ? INSZ - 1 : iy);
    xrow[ky] = xb + (size_t)iyc * INSZ * CINC;
  }

  // zero halo granules of all 4 buffers (s1: p0 and p OUTSZ+1; s2: p0 only)
  {
    constexpr int HGPB = (S == 1) ? 8 : 4;
    if (threadIdx.x < 4 * HGPB) {
      const int bi = threadIdx.x / HGPB, k = threadIdx.x % HGPB;
      const int g = (k < 4) ? k : (NGR - 8 + k);
      f16x8 z = {};
      *(f16x8*)&smem[bi * ROWF + g * 8] = z;
    }
  }

  f32x4 acc[4][4];
#pragma unroll
  for (int f = 0; f < 4; ++f)
#pragma unroll
    for (int g = 0; g < 4; ++g) acc[f][g] = (f32x4){0.f, 0.f, 0.f, 0.f};

  auto load_af = [&](int t, f16x8* af) {
    const int c = t / 3, kx = t % 3;
    const int ky = c / CH, ch = c % CH;
    const _Float16* wt = we + (size_t)(((ky * 3 + kx) * CH + ch) * 128) * 32;
#pragma unroll
    for (int f = 0; f < 4; ++f)
      af[f] = *(const f16x8*)&wt[(mwb + f * 16 + ln15) * 32 + quad * 8];
  };
  // interior = px 1..INSZ -> granules 4..4+INSZ*4-1
  auto stage = [&](int c, int bi) {
    const int ky = c / CH, ch = c % CH;
    _Float16* bufb = &smem[bi * ROWF];
    const _Float16* xr = xrow[ky];
#pragma unroll
    for (int s = 0; s < SPW; ++s) {
      const int seg = wv * SPW + s;
      const int gl = 4 + seg * 64 + lane;          // linear LDS granule
      const int gs = gl ^ ((gl >> 3) & 7);         // pre-swizzled source granule
      g2l16(xr + (size_t)((gs >> 2) - 1) * CINC + ch * 32 + (gs & 3) * 8,
            bufb + (4 + seg * 64) * 8);
    }
  };

  int gb[4];
#pragma unroll
  for (int g = 0; g < 4; ++g) {
    const int ox = nwb + g * 16 + ln15;
    gb[g] = 4 * S * ox + quad;                     // granule at kx 0
  }

  // af prefetch depth 2 (kept from R10 — measured good on conv3m)
  f16x8 afb[3][4];
  load_af(0, afb[0]);
  load_af(1, afb[1]);
  stage(0, 0);
  stage(1, 1);
  __syncthreads();

#pragma unroll
  for (int t = 0; t < NT; ++t) {
    const int c = t / 3, kx = t % 3;
    const int ky = c / CH;
    const int cur = c & 3;                         // 4-buffer rotation
    if (t + 2 < NT) load_af(t + 2, afb[(t + 2) % 3]);  // issued BEFORE stage
    if (kx == 0 && (c & 1) == 0) {                 // super-chunk: stage 2 ahead
      if (c + 2 < NCH) stage(c + 2, (c + 2) & 3);
      if (c + 3 < NCH) stage(c + 3, (c + 3) & 3);
    }
    if (rowok[ky]) {
      const _Float16* bufb = &smem[cur * ROWF];
#pragma unroll
      for (int g = 0; g < 4; ++g) {
        const int gq = gb[g] + 4 * kx;
        const int gs = gq ^ ((gq >> 3) & 7);
        const f16x8 bf = *(const f16x8*)&bufb[gs * 8];
#pragma unroll
        for (int f = 0; f < 4; ++f)
          acc[f][g] = __builtin_amdgcn_mfma_f32_16x16x32_f16(afb[t % 3][f], bf, acc[f][g], 0, 0, 0);
      }
    }
    if (kx == 2 && (c & 1)) __syncthreads();       // drain once per super-chunk
  }
  // NCH is even -> last chunk is odd -> barrier already executed before here.

  if constexpr (MODE == 2) {
    // ---- fused 1x1 head: out_oc = hb2[oc] + sum_c hw2[oc][c]*relu(acc+b1[c]) ----
    float p[4][5];
#pragma unroll
    for (int g = 0; g < 4; ++g)
#pragma unroll
      for (int oc = 0; oc < 5; ++oc) p[g][oc] = 0.f;
    const float* w2 = hw2 + (size_t)e * 5 * 128;
#pragma unroll
    for (int f = 0; f < 4; ++f) {
#pragma unroll
      for (int r = 0; r < 4; ++r) {
        const int cout = mwb + f * 16 + quad * 4 + r;
        const float bb = p_bias[e * 128 + cout];
        float w5[5];
#pragma unroll
        for (int oc = 0; oc < 5; ++oc) w5[oc] = w2[oc * 128 + cout];
#pragma unroll
        for (int g = 0; g < 4; ++g) {
          const float v = fmaxf(acc[f][g][r] + bb, 0.f);
#pragma unroll
          for (int oc = 0; oc < 5; ++oc) p[g][oc] = fmaf(w5[oc], v, p[g][oc]);
        }
      }
    }
    // reduce over the 4 quads (lanes ln15, ln15+16, ln15+32, ln15+48)
#pragma unroll
    for (int g = 0; g < 4; ++g)
#pragma unroll
      for (int oc = 0; oc < 5; ++oc) {
        float t0 = p[g][oc];
        t0 += __shfl_xor(t0, 16);
        t0 += __shfl_xor(t0, 32);
        p[g][oc] = t0;
      }
    // cross-wave reduce: waves (0,2) cover px 0..63, (1,3) cover 64..127
    float* sh = (float*)smem;
    if (quad == 0) {
#pragma unroll
      for (int g = 0; g < 4; ++g)
#pragma unroll
        for (int oc = 0; oc < 5; ++oc)
          sh[(wv * 64 + g * 16 + ln15) * 5 + oc] = p[g][oc];
    }
    __syncthreads();
    const int tid = threadIdx.x;
    if (tid < 128) {
      const int nw = tid >> 6, idx = tid & 63;
      float s[5];
#pragma unroll
      for (int oc = 0; oc < 5; ++oc)
        s[oc] = sh[(nw * 64 + idx) * 5 + oc] + sh[((nw + 2) * 64 + idx) * 5 + oc]
              + hb2[e * 5 + oc];
      const int pidx = oy * 128 + tid;
      hout[((size_t)b << 14) + pidx]                       = s[0];  // hm
      hout[131072 + ((size_t)(b * 2 + 0) << 14) + pidx]    = s[1];  // wh c0
      hout[131072 + ((size_t)(b * 2 + 1) << 14) + pidx]    = s[2];  // wh c1
      hout[393216 + ((size_t)(b * 2 + 0) << 14) + pidx]    = s[3];  // reg c0
      hout[393216 + ((size_t)(b * 2 + 1) << 14) + pidx]    = s[4];  // reg c1
    }
  } else {
    // ---- epilogue: relu -> LDS stage -> 128B half-line stores ----
    _Float16* sw = &smem[wv * 4608];
#pragma unroll
    for (int f = 0; f < 4; ++f) {
#pragma unroll
      for (int g = 0; g < 4; ++g) {
        f16x4 h;
#pragma unroll
        for (int r = 0; r < 4; ++r)
          h[r] = (_Float16)fmaxf(acc[f][g][r], 0.f);
        *(f16x4*)&sw[(g * 16 + ln15) * 72 + f * 16 + quad * 4] = h;
      }
    }
    __syncthreads();
    const size_t rowbase = ((size_t)(b * OUTSZ + oy) * OUTSZ + nwb) * 128 + mwb;
#pragma unroll
    for (int i = 0; i < 8; ++i) {
      const int pxl = (lane >> 3) + i * 8;
      const int c8  = (lane & 7) * 8;
      const f16x8 v = *(const f16x8*)&sw[pxl * 72 + c8];
      *(f16x8*)&out[rowbase + (size_t)pxl * 128 + c8] = v;
    }
  }
}

// ---------------- maxpool 3x3 s2 p1 (ch-last fp16) + partial mean ----------------
// R8: vectorized; R10: XCD swizzle. Packed f16 max is exact (inputs are f16).
__global__ __launch_bounds__(256) void pool_k(
    const _Float16* __restrict__ f, float* __restrict__ pooled)
{
  const int sb = xcd_swz(blockIdx.x, 1024);        // XCD owns one image's py range
  const int b  = sb >> 7;
  const int py = sb & 127;
  const int wv = threadIdx.x >> 6, lane = threadIdx.x & 63;
  const int c8  = (lane & 7) * 8;
  const int pxq = lane >> 3;
  const _Float16* fb = f + (size_t)b * 256 * 256 * 64;

  const int y0 = 2 * py - 1;
  float s[8];
#pragma unroll
  for (int j = 0; j < 8; ++j) s[j] = 0.f;

#pragma unroll
  for (int step = 0; step < 4; ++step) {
    const int px = wv * 32 + step * 8 + pxq;       // 0..127
    const int x0 = 2 * px - 1;
    f16x8 m;
#pragma unroll
    for (int j = 0; j < 8; ++j) m[j] = (_Float16)(-60000.f);
#pragma unroll
    for (int dy = 0; dy < 3; ++dy) {
      const int y = y0 + dy;
      if ((unsigned)y < 256u) {                    // wave-uniform (only py=0 clips)
        const _Float16* row = fb + (size_t)y * 256 * 64 + c8;
        if (x0 >= 0)                               // only px==0 lane clips
          m = __builtin_elementwise_max(m, *(const f16x8*)&row[(size_t)x0 * 64]);
        m = __builtin_elementwise_max(m, *(const f16x8*)&row[(size_t)(x0 + 1) * 64]);
        m = __builtin_elementwise_max(m, *(const f16x8*)&row[(size_t)(x0 + 2) * 64]);
      }
    }
#pragma unroll
    for (int j = 0; j < 8; ++j) s[j] += (float)m[j];
  }

  __shared__ float red[256][8];
#pragma unroll
  for (int j = 0; j < 8; ++j) red[threadIdx.x][j] = s[j];
  __syncthreads();
  if (threadIdx.x < 64) {
    const int c = threadIdx.x, cg = c >> 3, cj = c & 7;
    float t = 0.f;
#pragma unroll
    for (int k = 0; k < 32; ++k)                   // 4 waves x 8 px subgroups
      t += red[(k >> 3) * 64 + (k & 7) * 8 + cg][cj];
    atomicAdd(&pooled[b * 64 + c], t);
  }
}

// ---------------- FC + top-1 + aux loss (pooled holds SUMS; /16384) ----------------
__global__ __launch_bounds__(64) void gate_k(
    const float* __restrict__ pooled, const float* __restrict__ fcw,
    const float* __restrict__ fcb, int* __restrict__ sel, float* __restrict__ out_aux)
{
  __shared__ float probs[8][3];
  __shared__ int sidx[8];
  const int b = threadIdx.x;
  if (b < 8) {
    float l[3];
#pragma unroll
    for (int e = 0; e < 3; ++e) {
      float s = fcb[e];
      for (int c = 0; c < 64; ++c)
        s = fmaf(pooled[b * 64 + c] * (1.f / 16384.f), fcw[e * 64 + c], s);
      l[e] = s;
    }
    int best = 0;
    if (l[1] > l[best]) best = 1;
    if (l[2] > l[best]) best = 2;
    sel[b] = best;
    sidx[b] = best;
    const float m = fmaxf(l[0], fmaxf(l[1], l[2]));
    const float e0 = expf(l[0] - m), e1 = expf(l[1] - m), e2 = expf(l[2] - m);
    const float inv = 1.f / (e0 + e1 + e2);
    probs[b][0] = e0 * inv; probs[b][1] = e1 * inv; probs[b][2] = e2 * inv;
  }
  __syncthreads();
  if (threadIdx.x == 0) {
    float cnt[3] = {0.f, 0.f, 0.f}, pr[3] = {0.f, 0.f, 0.f};
    for (int bb = 0; bb < 8; ++bb) {
      cnt[sidx[bb]] += 1.f;
#pragma unroll
      for (int e = 0; e < 3; ++e) pr[e] += probs[bb][e];
    }
    float aux = 0.f;
#pragma unroll
    for (int e = 0; e < 3; ++e) aux += (cnt[e] * 0.125f) * (pr[e] * 0.125f);
    *out_aux = 0.01f * (3.f * aux);
  }
}

extern "C" void kernel_launch(void* const* d_in, const int* in_sizes, int n_in,
                              void* d_out, int out_size, void* d_ws, size_t ws_size,
                              hipStream_t stream) {
  const float* x          = (const float*)d_in[0];
  const float* g_conv_w   = (const float*)d_in[1];
  const float* g_bn_gamma = (const float*)d_in[2];
  const float* g_bn_beta  = (const float*)d_in[3];
  const float* g_bn_mean  = (const float*)d_in[4];
  const float* g_bn_var   = (const float*)d_in[5];
  const float* g_fc_w     = (const float*)d_in[6];
  const float* g_fc_b     = (const float*)d_in[7];
  const float* e_conv1_w  = (const float*)d_in[8];
  const float* e_conv2_w  = (const float*)d_in[9];
  const float* e_head_w1  = (const float*)d_in[10];
  const float* e_head_b1  = (const float*)d_in[11];
  const float* e_head_w2  = (const float*)d_in[12];
  const float* e_head_b2  = (const float*)d_in[13];
  float* out = (float*)d_out;

  // ---- workspace layout (f16 units), total ~170 MB ----
  _Float16* xp      = (_Float16*)d_ws;             // 8*512*512*16 = 33,554,432
  _Float16* featbuf = xp + 33554432;               // 8*256*256*64 = 33,554,432
  _Float16* y2      = featbuf + 33554432;          // 8*128*128*128 = 16,777,216
  _Float16* w7p     = y2 + 16777216;               // 229,376
  _Float16* w2p     = w7p + 229376;                // 221,184
  _Float16* w3p     = w2p + 221184;                // 442,368
  float*    pooled  = (float*)(w3p + 442368);      // 512 f32
  int*      sel     = (int*)(pooled + 512);        // 8 ints

  // ---- preps (merged: w7 + w2 + w3 + pooled zero in one dispatch) ----
  prep_x_k<<<2048, 256, 0, stream>>>(x, xp);
  prep_w_k<<<3489, 256, 0, stream>>>(g_conv_w, e_conv1_w, e_conv2_w, e_head_w1,
                                     w7p, w2p, w3p, pooled);

  // ---- gating path ----
  conv7m_k<0, 1><<<2048, 256, 0, stream>>>(xp, w7p, g_bn_gamma, g_bn_beta,
                                           g_bn_mean, g_bn_var, nullptr, featbuf);
  pool_k<<<1024, 256, 0, stream>>>(featbuf, pooled);
  gate_k<<<1, 64, 0, stream>>>(pooled, g_fc_w, g_fc_b, sel, out + 655360);

  // ---- selected-expert path ----
  conv7m_k<1, 1><<<2048, 256, 0, stream>>>(xp, w7p, nullptr, nullptr, nullptr, nullptr,
                                           sel, featbuf);
  conv3m_k<64, 2, 256, 128, 1><<<1024, 256, 0, stream>>>(
      featbuf, w2p, nullptr, sel, y2, nullptr, nullptr, nullptr);
  conv3m_k<128, 1, 128, 128, 2><<<1024, 256, 0, stream>>>(
      y2, w3p, e_head_b1, sel, nullptr, e_head_w2, e_head_b2, out);
}